// Round 12
// baseline (257.223 us; speedup 1.0000x reference)
//
#include <hip/hip_runtime.h>
#include <hip/hip_bf16.h>

// Problem constants
#define BB 2
#define LL 4096
#define DD 256
#define KK 16
#define GG 4
#define HH 8
#define DH 64
#define PE 32
#define INNER 512          // H*DH
#define CC 21              // 1 + K + G
#define MM (BB*LL)         // 8192
#define SCALE 0.125f
#define NT1 1792           // QKVT GEMM N  (Q|K|V|T)
#define KT1 256
#define NT2 256            // out GEMM N
#define KT2 768

typedef unsigned short u16;
typedef __attribute__((ext_vector_type(8))) short bf16x8;
typedef __attribute__((ext_vector_type(4))) float f32x4;
typedef unsigned short ushort4_t __attribute__((ext_vector_type(4)));
typedef unsigned short ushort8_t __attribute__((ext_vector_type(8)));

static __device__ __forceinline__ float bf2f(unsigned short u) {
    return __uint_as_float(((unsigned)u) << 16);
}
static __device__ __forceinline__ unsigned short f2bf(float f) {
    unsigned u = __float_as_uint(f);
    unsigned r = u + 0x7fffu + ((u >> 16) & 1u);   // RNE
    return (unsigned short)(r >> 16);
}
static __device__ __forceinline__ void gld_lds16(const void* g, void* l) {
    __builtin_amdgcn_global_load_lds(
        (const __attribute__((address_space(1))) unsigned int*)g,
        (__attribute__((address_space(3))) unsigned int*)l, 16, 0, 0);
}

// 8-lane group sum via DPP (pure VALU, no DS ops).
// xor1 = quad_perm [1,0,3,2] (0xB1); xor2 = quad_perm [2,3,0,1] (0x4E);
// after quad reduction the value is quad-uniform, so row_half_mirror
// (lane ^ 7, 0x141) is equivalent to lane ^ 4.
static __device__ __forceinline__ float red8_dpp(float x) {
    int xi = __float_as_int(x);
    x += __int_as_float(__builtin_amdgcn_update_dpp(0, xi, 0xB1, 0xF, 0xF, true));
    xi = __float_as_int(x);
    x += __int_as_float(__builtin_amdgcn_update_dpp(0, xi, 0x4E, 0xF, 0xF, true));
    xi = __float_as_int(x);
    x += __int_as_float(__builtin_amdgcn_update_dpp(0, xi, 0x141, 0xF, 0xF, true));
    return x;
}

// ---------------------------------------------------------------------------
// megaprep1: fuses prep_A | prep_M2 | cast_spatial | gemm_globals
// ---------------------------------------------------------------------------
__global__ __launch_bounds__(256) void megaprep1(
    const float* __restrict__ Wq, const float* __restrict__ Wk,
    const float* __restrict__ Wv, const float* __restrict__ Wo,
    const float* __restrict__ spatial, const float* __restrict__ gl,
    float* __restrict__ A, float* __restrict__ M2, u16* __restrict__ Sb,
    u16* __restrict__ Kg, u16* __restrict__ Vg)
{
    const int bid = blockIdx.x;
    const int tid = threadIdx.x;
    __shared__ float smem[INNER];

    if (bid < 256) {                       // ---- prep_A
        const int e = bid;
        smem[tid]       = Wq[e * INNER + tid];
        smem[tid + 256] = Wq[e * INNER + 256 + tid];
        __syncthreads();
        const int h = tid >> 5, p = tid & 31;
        const float* __restrict__ wr = &Wk[(size_t)(DD + p) * INNER + h * DH];
        const float* __restrict__ qh = &smem[h * DH];
        float s = 0.f;
        #pragma unroll 8
        for (int d = 0; d < DH; ++d) s += wr[d] * qh[d];
        A[e * 256 + tid] = s;
    } else if (bid < 512) {                // ---- prep_M2
        const int hp = bid - 256;
        const int h = hp >> 5, p = hp & 31;
        if (tid < DH) smem[tid] = Wv[(size_t)(DD + p) * INNER + h * DH + tid];
        __syncthreads();
        float s = 0.f;
        #pragma unroll 8
        for (int d = 0; d < DH; ++d) s += smem[d] * Wo[(size_t)(h * DH + d) * DD + tid];
        M2[hp * 256 + tid] = s;
    } else if (bid < 1536) {               // ---- cast_spatial
        const size_t i = ((size_t)(bid - 512) * 256 + tid) * 8;
        float4 a = *reinterpret_cast<const float4*>(&spatial[i]);
        float4 b = *reinterpret_cast<const float4*>(&spatial[i + 4]);
        ushort8_t v = { f2bf(a.x), f2bf(a.y), f2bf(a.z), f2bf(a.w),
                        f2bf(b.x), f2bf(b.y), f2bf(b.z), f2bf(b.w) };
        *reinterpret_cast<ushort8_t*>(&Sb[i]) = v;
    } else {                               // ---- gemm_globals
        const int local = bid - 1536;
        const int bg = local >> 2;
        const int col = (local & 3) * 128 + (tid & 127);
        const bool isv = tid >= 128;
        const float* __restrict__ W = isv ? Wv : Wk;
        const float* __restrict__ x = &gl[bg * DD];
        float s = 0.f;
        #pragma unroll 4
        for (int k = 0; k < DD; ++k) s += x[k] * W[(size_t)k * INNER + col];
        if (isv) Vg[bg * INNER + col] = f2bf(s);
        else     Kg[bg * INNER + col] = f2bf(s);
    }
}

// ---------------------------------------------------------------------------
// megaprep2: fuses the two weight transposes (64x64 LDS tiles)
// ---------------------------------------------------------------------------
__global__ __launch_bounds__(256) void megaprep2(
    const float* __restrict__ Wq, const float* __restrict__ Wk,
    const float* __restrict__ Wv, const float* __restrict__ A,
    const float* __restrict__ Wo, const float* __restrict__ M2,
    u16* __restrict__ Wt, u16* __restrict__ Wot)
{
    __shared__ float tile[64][65];
    const int bid = blockIdx.x;
    const int tid = threadIdx.x;

    const float* src; int ld, nloc, n0, k0, ldo; u16* dstbase; int kt;
    if (bid < 112) {
        n0 = (bid % 28) * 64; k0 = (bid / 28) * 64;
        if (n0 < 512)       { src = Wq; ld = INNER; nloc = n0; }
        else if (n0 < 1024) { src = Wk; ld = INNER; nloc = n0 - 512; }
        else if (n0 < 1536) { src = Wv; ld = INNER; nloc = n0 - 1024; }
        else                { src = A;  ld = 256;   nloc = n0 - 1536; }
        dstbase = Wt; ldo = KT1; kt = k0;
    } else {
        const int local = bid - 112;
        n0 = (local % 4) * 64; k0 = (local / 4) * 64;
        if (k0 < 512) { src = Wo; kt = k0; }
        else          { src = M2; kt = k0 - 512; }
        ld = DD; nloc = n0;
        dstbase = Wot; ldo = KT2;
    }

    const int tk = tid >> 4;
    const int tn = (tid & 15) * 4;
    #pragma unroll
    for (int rep = 0; rep < 4; ++rep) {
        const int k = kt + tk + rep * 16;
        float4 v = *reinterpret_cast<const float4*>(&src[(size_t)k * ld + nloc + tn]);
        tile[tk + rep * 16][tn + 0] = v.x; tile[tk + rep * 16][tn + 1] = v.y;
        tile[tk + rep * 16][tn + 2] = v.z; tile[tk + rep * 16][tn + 3] = v.w;
    }
    __syncthreads();
    const int wn = tid >> 2;
    const int wk = (tid & 3) * 16;
    ushort8_t o0, o1;
    #pragma unroll
    for (int i = 0; i < 8; ++i) o0[i] = f2bf(tile[wk + i][wn]);
    #pragma unroll
    for (int i = 0; i < 8; ++i) o1[i] = f2bf(tile[wk + 8 + i][wn]);
    u16* dst = &dstbase[(size_t)(n0 + wn) * ldo + k0 + wk];
    *reinterpret_cast<ushort8_t*>(dst)     = o0;
    *reinterpret_cast<ushort8_t*>(dst + 8) = o1;
}

// ---------------------------------------------------------------------------
// mfma_gemm (unchanged, proven)
// ---------------------------------------------------------------------------
template<int KT, int LDA, int NTOT, int BN, bool F32OUT>
__global__ __launch_bounds__(256) void mfma_gemm(
    const u16* __restrict__ A, const u16* __restrict__ Bt,
    u16* __restrict__ outB, float* __restrict__ outF,
    const float* __restrict__ bias)
{
    constexpr int WNT = BN / 2;
    constexpr int BJ  = WNT / 16;
    constexpr int BCH = BN / 8;

    __shared__ u16 As[128 * 64];
    __shared__ u16 Bs[BN * 64];

    const int tid  = threadIdx.x;
    const int lane = tid & 63;
    const int w    = tid >> 6;
    const int wr   = w >> 1, wc = w & 1;
    const int m0 = blockIdx.x * 128;
    const int n0 = blockIdx.y * BN;
    const int fr = lane & 15, fq = lane >> 4;

    f32x4 acc[4][BJ];
    #pragma unroll
    for (int i = 0; i < 4; ++i)
        #pragma unroll
        for (int j = 0; j < BJ; ++j)
            acc[i][j] = (f32x4){0.f, 0.f, 0.f, 0.f};

    for (int t = 0; t < KT / 64; ++t) {
        const int k0 = t * 64;
        #pragma unroll
        for (int cc = 0; cc < 4; ++cc) {
            const int chunk = w + cc * 4;
            gld_lds16(A + (size_t)(m0 + chunk * 8 + (lane >> 3)) * LDA + k0 + (lane & 7) * 8,
                      (char*)&As[0] + chunk * 1024);
        }
        #pragma unroll
        for (int cc = 0; cc < BCH / 4; ++cc) {
            const int chunk = w + cc * 4;
            gld_lds16(Bt + (size_t)(n0 + chunk * 8 + (lane >> 3)) * KT + k0 + (lane & 7) * 8,
                      (char*)&Bs[0] + chunk * 1024);
        }
        __syncthreads();
        #pragma unroll
        for (int ks = 0; ks < 2; ++ks) {
            bf16x8 av[4], bv[BJ];
            #pragma unroll
            for (int i = 0; i < 4; ++i)
                av[i] = *reinterpret_cast<const bf16x8*>(
                    &As[(wr * 64 + i * 16 + fr) * 64 + ks * 32 + fq * 8]);
            #pragma unroll
            for (int j = 0; j < BJ; ++j)
                bv[j] = *reinterpret_cast<const bf16x8*>(
                    &Bs[(wc * WNT + j * 16 + fr) * 64 + ks * 32 + fq * 8]);
            #pragma unroll
            for (int i = 0; i < 4; ++i)
                #pragma unroll
                for (int j = 0; j < BJ; ++j)
                    acc[i][j] = __builtin_amdgcn_mfma_f32_16x16x32_bf16(
                        av[i], bv[j], acc[i][j], 0, 0, 0);
        }
        __syncthreads();
    }

    #pragma unroll
    for (int i = 0; i < 4; ++i)
        #pragma unroll
        for (int j = 0; j < BJ; ++j)
            #pragma unroll
            for (int rgi = 0; rgi < 4; ++rgi) {
                const int row = m0 + wr * 64 + i * 16 + fq * 4 + rgi;
                const int col = n0 + wc * WNT + j * 16 + fr;
                if constexpr (F32OUT)
                    outF[(size_t)row * NTOT + col] = acc[i][j][rgi] + bias[col];
                else
                    outB[(size_t)row * NTOT + col] = f2bf(acc[i][j][rgi]);
            }
}

// ---------------------------------------------------------------------------
// attn: one wave per query, single-pass no-max softmax (R11 structure).
// Changes vs R11:
//  - 8-lane reduce via DPP (pure VALU) instead of __shfl_xor (DS pipe).
//  - __launch_bounds__(256,5): VGPR cap 102 (between R8's 84 and R11's 128;
//    min live state ~70 so no spill; raises wave cap 4->5 per SIMD).
// ---------------------------------------------------------------------------
__global__ __launch_bounds__(256, 5) void attn_kernel(
    const u16* __restrict__ X, const u16* __restrict__ Kg,
    const u16* __restrict__ Vg, const int* __restrict__ topk,
    const float* __restrict__ rpe, const float* __restrict__ self_rpe,
    const float* __restrict__ distances, const float* __restrict__ log_sigma,
    const float* __restrict__ global_bias, u16* __restrict__ ob2)
{
    const int lane = threadIdx.x & 63;
    const int bid  = blockIdx.x;
    const int xcd  = bid & 7;
    const int slot = bid >> 3;                       // 0..255
    const int qblk = (xcd >> 2) * 1024 + slot * 4 + (xcd & 3);
    const int q = __builtin_amdgcn_readfirstlane(qblk * 4 + (threadIdx.x >> 6));
    const int b = q >> 12;
    const int h = lane >> 3;
    const int r = lane & 7;
    const int qk = q * KK;
    const size_t bL = (size_t)b * LL;
    const int bG = b * GG;

    // Q slice (bf16 -> f32 regs)
    float qf[8];
    {
        ushort8_t qv = *reinterpret_cast<const ushort8_t*>(&X[(size_t)q * NT1 + lane * 8]);
        #pragma unroll
        for (int j = 0; j < 8; ++j) qf[j] = bf2f(qv[j]);
    }
    // t4
    float t4[4];
    {
        ushort4_t tu = *reinterpret_cast<const ushort4_t*>(
            &X[(size_t)q * NT1 + 1536 + h * 32 + r * 4]);
        t4[0] = bf2f(tu[0]); t4[1] = bf2f(tu[1]);
        t4[2] = bf2f(tu[2]); t4[3] = bf2f(tu[3]);
    }

    const float inv2sig = 0.5f * __expf(-2.f * log_sigma[h]);
    const float gbias   = global_bias[0];

    float denom = 0.f;
    float acc[8] = {0.f,0.f,0.f,0.f,0.f,0.f,0.f,0.f};
    float rb[4]  = {0.f,0.f,0.f,0.f};

    #pragma unroll
    for (int c = 0; c < CC; ++c) {
        const u16 *kb, *vb;
        const float* rp_ = nullptr;
        float biasc;
        if (c == 0) {
            kb = &X[(size_t)q * NT1 + 512];
            vb = &X[(size_t)q * NT1 + 1024];
            rp_ = &self_rpe[(size_t)q * PE];
            biasc = 0.f;
        } else if (c < 17) {
            const int idx = topk[qk + c - 1];              // s_load (uniform)
            kb = &X[(bL + idx) * NT1 + 512];
            vb = &X[(bL + idx) * NT1 + 1024];
            rp_ = &rpe[((size_t)qk + (c - 1)) * PE];
            const float d = distances[qk + c - 1];         // s_load (uniform)
            biasc = -(d * d) * inv2sig;
        } else {
            kb = &Kg[(size_t)(bG + c - 17) * INNER];
            vb = &Vg[(size_t)(bG + c - 17) * INNER];
            biasc = gbias;
        }
        ushort8_t kv = *reinterpret_cast<const ushort8_t*>(kb + lane * 8);
        ushort8_t vv = *reinterpret_cast<const ushort8_t*>(vb + lane * 8);
        float4 r4 = {0.f,0.f,0.f,0.f};
        if (c < 17) r4 = *reinterpret_cast<const float4*>(rp_ + r * 4);

        float part = bf2f(kv[0])*qf[0] + bf2f(kv[1])*qf[1]
                   + bf2f(kv[2])*qf[2] + bf2f(kv[3])*qf[3]
                   + bf2f(kv[4])*qf[4] + bf2f(kv[5])*qf[5]
                   + bf2f(kv[6])*qf[6] + bf2f(kv[7])*qf[7];
        if (c < 17)
            part += r4.x*t4[0] + r4.y*t4[1] + r4.z*t4[2] + r4.w*t4[3];
        part = red8_dpp(part);                             // DPP, no DS ops

        const float e = __expf(part * SCALE + biasc);      // no max needed
        denom += e;
        #pragma unroll
        for (int i = 0; i < 8; ++i) acc[i] += e * bf2f(vv[i]);
        if (c < 17) {
            rb[0] += e * r4.x; rb[1] += e * r4.y;
            rb[2] += e * r4.z; rb[3] += e * r4.w;
        }
    }

    const float inv = 1.f / denom;
    ushort4_t ru = { f2bf(rb[0]*inv), f2bf(rb[1]*inv), f2bf(rb[2]*inv), f2bf(rb[3]*inv) };
    *reinterpret_cast<ushort4_t*>(&ob2[(size_t)q * KT2 + 512 + h * 32 + r * 4]) = ru;
    ushort8_t ou = { f2bf(acc[0]*inv), f2bf(acc[1]*inv), f2bf(acc[2]*inv), f2bf(acc[3]*inv),
                     f2bf(acc[4]*inv), f2bf(acc[5]*inv), f2bf(acc[6]*inv), f2bf(acc[7]*inv) };
    *reinterpret_cast<ushort8_t*>(&ob2[(size_t)q * KT2 + lane * 8]) = ou;
}

// ---------------------------------------------------------------------------
extern "C" void kernel_launch(void* const* d_in, const int* in_sizes, int n_in,
                              void* d_out, int out_size, void* d_ws, size_t ws_size,
                              hipStream_t stream)
{
    const float* spatial     = (const float*)d_in[0];
    const int*   topk        = (const int*)  d_in[1];
    const float* rpe         = (const float*)d_in[2];
    const float* self_rpe    = (const float*)d_in[3];
    const float* distances   = (const float*)d_in[4];
    const float* gl          = (const float*)d_in[5];
    const float* Wq          = (const float*)d_in[6];
    const float* Wk          = (const float*)d_in[7];
    const float* Wv          = (const float*)d_in[8];
    const float* Wo          = (const float*)d_in[9];
    const float* bo          = (const float*)d_in[10];
    const float* log_sigma   = (const float*)d_in[11];
    const float* global_bias = (const float*)d_in[12];
    float* out = (float*)d_out;

    char* p = (char*)d_ws;
    float* A   = (float*)p;  p += (size_t)256 * 256 * 4;
    float* M2  = (float*)p;  p += (size_t)256 * 256 * 4;
    u16* Sb    = (u16*)p;    p += (size_t)MM * DD * 2;
    u16* Wt    = (u16*)p;    p += (size_t)NT1 * KT1 * 2;
    u16* Wot   = (u16*)p;    p += (size_t)NT2 * KT2 * 2;
    u16* X     = (u16*)p;    p += (size_t)MM * NT1 * 2;
    u16* ob2   = (u16*)p;    p += (size_t)MM * KT2 * 2;
    u16* Kg    = (u16*)p;    p += (size_t)BB * GG * INNER * 2;
    u16* Vg    = (u16*)p;    p += (size_t)BB * GG * INNER * 2;

    megaprep1<<<1568, 256, 0, stream>>>(Wq, Wk, Wv, Wo, spatial, gl,
                                        A, M2, Sb, Kg, Vg);
    megaprep2<<<160, 256, 0, stream>>>(Wq, Wk, Wv, A, Wo, M2, Wt, Wot);

    mfma_gemm<KT1, 256, NT1, 128, false><<<dim3(MM / 128, NT1 / 128), 256, 0, stream>>>(
        Sb, Wt, X, nullptr, nullptr);

    attn_kernel<<<MM / 4, 256, 0, stream>>>(
        X, Kg, Vg, topk, rpe, self_rpe, distances, log_sigma, global_bias, ob2);

    // BN=32 -> 512 blocks (2/CU) instead of 256 (1/CU): overlap staging drains
    mfma_gemm<KT2, KT2, NT2, 32, true><<<dim3(MM / 128, NT2 / 32), 256, 0, stream>>>(
        ob2, Wot, nullptr, out, bo);
}

// Round 13
// 97.340 us; speedup vs baseline: 2.6425x; 2.6425x over previous
//
#include <hip/hip_runtime.h>
#include <hip/hip_bf16.h>

// Problem constants
#define BB 2
#define LL 4096
#define DD 256
#define KK 16
#define GG 4
#define HH 8
#define DH 64
#define PE 32
#define INNER 512          // H*DH
#define CC 21              // 1 + K + G
#define MM (BB*LL)         // 8192
#define SCALE 0.125f
#define NT1 1792           // QKVT GEMM N  (Q|K|V|T)
#define KT1 256
#define NT2 256            // out GEMM N
#define KT2 768

typedef unsigned short u16;
typedef __attribute__((ext_vector_type(8))) short bf16x8;
typedef __attribute__((ext_vector_type(4))) float f32x4;
typedef unsigned short ushort4_t __attribute__((ext_vector_type(4)));
typedef unsigned short ushort8_t __attribute__((ext_vector_type(8)));

static __device__ __forceinline__ float bf2f(unsigned short u) {
    return __uint_as_float(((unsigned)u) << 16);
}
static __device__ __forceinline__ unsigned short f2bf(float f) {
    unsigned u = __float_as_uint(f);
    unsigned r = u + 0x7fffu + ((u >> 16) & 1u);   // RNE
    return (unsigned short)(r >> 16);
}
static __device__ __forceinline__ void gld_lds16(const void* g, void* l) {
    __builtin_amdgcn_global_load_lds(
        (const __attribute__((address_space(1))) unsigned int*)g,
        (__attribute__((address_space(3))) unsigned int*)l, 16, 0, 0);
}

// 8-lane group sum via DPP (pure VALU, no DS ops).
// xor1 = quad_perm [1,0,3,2] (0xB1); xor2 = quad_perm [2,3,0,1] (0x4E);
// after quad reduction the value is quad-uniform, so row_half_mirror
// (lane ^ 7, 0x141) is equivalent to lane ^ 4.
static __device__ __forceinline__ float red8_dpp(float x) {
    int xi = __float_as_int(x);
    x += __int_as_float(__builtin_amdgcn_update_dpp(0, xi, 0xB1, 0xF, 0xF, true));
    xi = __float_as_int(x);
    x += __int_as_float(__builtin_amdgcn_update_dpp(0, xi, 0x4E, 0xF, 0xF, true));
    xi = __float_as_int(x);
    x += __int_as_float(__builtin_amdgcn_update_dpp(0, xi, 0x141, 0xF, 0xF, true));
    return x;
}

// ---------------------------------------------------------------------------
// megaprep1: fuses prep_A | prep_M2 | cast_spatial | gemm_globals
// ---------------------------------------------------------------------------
__global__ __launch_bounds__(256) void megaprep1(
    const float* __restrict__ Wq, const float* __restrict__ Wk,
    const float* __restrict__ Wv, const float* __restrict__ Wo,
    const float* __restrict__ spatial, const float* __restrict__ gl,
    float* __restrict__ A, float* __restrict__ M2, u16* __restrict__ Sb,
    u16* __restrict__ Kg, u16* __restrict__ Vg)
{
    const int bid = blockIdx.x;
    const int tid = threadIdx.x;
    __shared__ float smem[INNER];

    if (bid < 256) {                       // ---- prep_A
        const int e = bid;
        smem[tid]       = Wq[e * INNER + tid];
        smem[tid + 256] = Wq[e * INNER + 256 + tid];
        __syncthreads();
        const int h = tid >> 5, p = tid & 31;
        const float* __restrict__ wr = &Wk[(size_t)(DD + p) * INNER + h * DH];
        const float* __restrict__ qh = &smem[h * DH];
        float s = 0.f;
        #pragma unroll 8
        for (int d = 0; d < DH; ++d) s += wr[d] * qh[d];
        A[e * 256 + tid] = s;
    } else if (bid < 512) {                // ---- prep_M2
        const int hp = bid - 256;
        const int h = hp >> 5, p = hp & 31;
        if (tid < DH) smem[tid] = Wv[(size_t)(DD + p) * INNER + h * DH + tid];
        __syncthreads();
        float s = 0.f;
        #pragma unroll 8
        for (int d = 0; d < DH; ++d) s += smem[d] * Wo[(size_t)(h * DH + d) * DD + tid];
        M2[hp * 256 + tid] = s;
    } else if (bid < 1536) {               // ---- cast_spatial
        const size_t i = ((size_t)(bid - 512) * 256 + tid) * 8;
        float4 a = *reinterpret_cast<const float4*>(&spatial[i]);
        float4 b = *reinterpret_cast<const float4*>(&spatial[i + 4]);
        ushort8_t v = { f2bf(a.x), f2bf(a.y), f2bf(a.z), f2bf(a.w),
                        f2bf(b.x), f2bf(b.y), f2bf(b.z), f2bf(b.w) };
        *reinterpret_cast<ushort8_t*>(&Sb[i]) = v;
    } else {                               // ---- gemm_globals
        const int local = bid - 1536;
        const int bg = local >> 2;
        const int col = (local & 3) * 128 + (tid & 127);
        const bool isv = tid >= 128;
        const float* __restrict__ W = isv ? Wv : Wk;
        const float* __restrict__ x = &gl[bg * DD];
        float s = 0.f;
        #pragma unroll 4
        for (int k = 0; k < DD; ++k) s += x[k] * W[(size_t)k * INNER + col];
        if (isv) Vg[bg * INNER + col] = f2bf(s);
        else     Kg[bg * INNER + col] = f2bf(s);
    }
}

// ---------------------------------------------------------------------------
// megaprep2: fuses the two weight transposes (64x64 LDS tiles)
// ---------------------------------------------------------------------------
__global__ __launch_bounds__(256) void megaprep2(
    const float* __restrict__ Wq, const float* __restrict__ Wk,
    const float* __restrict__ Wv, const float* __restrict__ A,
    const float* __restrict__ Wo, const float* __restrict__ M2,
    u16* __restrict__ Wt, u16* __restrict__ Wot)
{
    __shared__ float tile[64][65];
    const int bid = blockIdx.x;
    const int tid = threadIdx.x;

    const float* src; int ld, nloc, n0, k0, ldo; u16* dstbase; int kt;
    if (bid < 112) {
        n0 = (bid % 28) * 64; k0 = (bid / 28) * 64;
        if (n0 < 512)       { src = Wq; ld = INNER; nloc = n0; }
        else if (n0 < 1024) { src = Wk; ld = INNER; nloc = n0 - 512; }
        else if (n0 < 1536) { src = Wv; ld = INNER; nloc = n0 - 1024; }
        else                { src = A;  ld = 256;   nloc = n0 - 1536; }
        dstbase = Wt; ldo = KT1; kt = k0;
    } else {
        const int local = bid - 112;
        n0 = (local % 4) * 64; k0 = (local / 4) * 64;
        if (k0 < 512) { src = Wo; kt = k0; }
        else          { src = M2; kt = k0 - 512; }
        ld = DD; nloc = n0;
        dstbase = Wot; ldo = KT2;
    }

    const int tk = tid >> 4;
    const int tn = (tid & 15) * 4;
    #pragma unroll
    for (int rep = 0; rep < 4; ++rep) {
        const int k = kt + tk + rep * 16;
        float4 v = *reinterpret_cast<const float4*>(&src[(size_t)k * ld + nloc + tn]);
        tile[tk + rep * 16][tn + 0] = v.x; tile[tk + rep * 16][tn + 1] = v.y;
        tile[tk + rep * 16][tn + 2] = v.z; tile[tk + rep * 16][tn + 3] = v.w;
    }
    __syncthreads();
    const int wn = tid >> 2;
    const int wk = (tid & 3) * 16;
    ushort8_t o0, o1;
    #pragma unroll
    for (int i = 0; i < 8; ++i) o0[i] = f2bf(tile[wk + i][wn]);
    #pragma unroll
    for (int i = 0; i < 8; ++i) o1[i] = f2bf(tile[wk + 8 + i][wn]);
    u16* dst = &dstbase[(size_t)(n0 + wn) * ldo + k0 + wk];
    *reinterpret_cast<ushort8_t*>(dst)     = o0;
    *reinterpret_cast<ushort8_t*>(dst + 8) = o1;
}

// ---------------------------------------------------------------------------
// mfma_gemm (unchanged, proven)
// ---------------------------------------------------------------------------
template<int KT, int LDA, int NTOT, int BN, bool F32OUT>
__global__ __launch_bounds__(256) void mfma_gemm(
    const u16* __restrict__ A, const u16* __restrict__ Bt,
    u16* __restrict__ outB, float* __restrict__ outF,
    const float* __restrict__ bias)
{
    constexpr int WNT = BN / 2;
    constexpr int BJ  = WNT / 16;
    constexpr int BCH = BN / 8;

    __shared__ u16 As[128 * 64];
    __shared__ u16 Bs[BN * 64];

    const int tid  = threadIdx.x;
    const int lane = tid & 63;
    const int w    = tid >> 6;
    const int wr   = w >> 1, wc = w & 1;
    const int m0 = blockIdx.x * 128;
    const int n0 = blockIdx.y * BN;
    const int fr = lane & 15, fq = lane >> 4;

    f32x4 acc[4][BJ];
    #pragma unroll
    for (int i = 0; i < 4; ++i)
        #pragma unroll
        for (int j = 0; j < BJ; ++j)
            acc[i][j] = (f32x4){0.f, 0.f, 0.f, 0.f};

    for (int t = 0; t < KT / 64; ++t) {
        const int k0 = t * 64;
        #pragma unroll
        for (int cc = 0; cc < 4; ++cc) {
            const int chunk = w + cc * 4;
            gld_lds16(A + (size_t)(m0 + chunk * 8 + (lane >> 3)) * LDA + k0 + (lane & 7) * 8,
                      (char*)&As[0] + chunk * 1024);
        }
        #pragma unroll
        for (int cc = 0; cc < BCH / 4; ++cc) {
            const int chunk = w + cc * 4;
            gld_lds16(Bt + (size_t)(n0 + chunk * 8 + (lane >> 3)) * KT + k0 + (lane & 7) * 8,
                      (char*)&Bs[0] + chunk * 1024);
        }
        __syncthreads();
        #pragma unroll
        for (int ks = 0; ks < 2; ++ks) {
            bf16x8 av[4], bv[BJ];
            #pragma unroll
            for (int i = 0; i < 4; ++i)
                av[i] = *reinterpret_cast<const bf16x8*>(
                    &As[(wr * 64 + i * 16 + fr) * 64 + ks * 32 + fq * 8]);
            #pragma unroll
            for (int j = 0; j < BJ; ++j)
                bv[j] = *reinterpret_cast<const bf16x8*>(
                    &Bs[(wc * WNT + j * 16 + fr) * 64 + ks * 32 + fq * 8]);
            #pragma unroll
            for (int i = 0; i < 4; ++i)
                #pragma unroll
                for (int j = 0; j < BJ; ++j)
                    acc[i][j] = __builtin_amdgcn_mfma_f32_16x16x32_bf16(
                        av[i], bv[j], acc[i][j], 0, 0, 0);
        }
        __syncthreads();
    }

    #pragma unroll
    for (int i = 0; i < 4; ++i)
        #pragma unroll
        for (int j = 0; j < BJ; ++j)
            #pragma unroll
            for (int rgi = 0; rgi < 4; ++rgi) {
                const int row = m0 + wr * 64 + i * 16 + fq * 4 + rgi;
                const int col = n0 + wc * WNT + j * 16 + fr;
                if constexpr (F32OUT)
                    outF[(size_t)row * NTOT + col] = acc[i][j][rgi] + bias[col];
                else
                    outB[(size_t)row * NTOT + col] = f2bf(acc[i][j][rgi]);
            }
}

// ---------------------------------------------------------------------------
// attn: one wave per query, single-pass no-max softmax (R11 structure),
// DPP 8-lane reduction, NATURAL register allocation (no min-waves bound:
// both (256,8) [R10: VGPR 32] and (256,5) [R12: VGPR 48] made the allocator
// collapse the budget and spill hundreds of MB of scratch).
// ---------------------------------------------------------------------------
__global__ __launch_bounds__(256) void attn_kernel(
    const u16* __restrict__ X, const u16* __restrict__ Kg,
    const u16* __restrict__ Vg, const int* __restrict__ topk,
    const float* __restrict__ rpe, const float* __restrict__ self_rpe,
    const float* __restrict__ distances, const float* __restrict__ log_sigma,
    const float* __restrict__ global_bias, u16* __restrict__ ob2)
{
    const int lane = threadIdx.x & 63;
    const int bid  = blockIdx.x;
    const int xcd  = bid & 7;
    const int slot = bid >> 3;                       // 0..255
    const int qblk = (xcd >> 2) * 1024 + slot * 4 + (xcd & 3);
    const int q = __builtin_amdgcn_readfirstlane(qblk * 4 + (threadIdx.x >> 6));
    const int b = q >> 12;
    const int h = lane >> 3;
    const int r = lane & 7;
    const int qk = q * KK;
    const size_t bL = (size_t)b * LL;
    const int bG = b * GG;

    // Q slice (bf16 -> f32 regs)
    float qf[8];
    {
        ushort8_t qv = *reinterpret_cast<const ushort8_t*>(&X[(size_t)q * NT1 + lane * 8]);
        #pragma unroll
        for (int j = 0; j < 8; ++j) qf[j] = bf2f(qv[j]);
    }
    // t4
    float t4[4];
    {
        ushort4_t tu = *reinterpret_cast<const ushort4_t*>(
            &X[(size_t)q * NT1 + 1536 + h * 32 + r * 4]);
        t4[0] = bf2f(tu[0]); t4[1] = bf2f(tu[1]);
        t4[2] = bf2f(tu[2]); t4[3] = bf2f(tu[3]);
    }

    const float inv2sig = 0.5f * __expf(-2.f * log_sigma[h]);
    const float gbias   = global_bias[0];

    float denom = 0.f;
    float acc[8] = {0.f,0.f,0.f,0.f,0.f,0.f,0.f,0.f};
    float rb[4]  = {0.f,0.f,0.f,0.f};

    #pragma unroll
    for (int c = 0; c < CC; ++c) {
        const u16 *kb, *vb;
        const float* rp_ = nullptr;
        float biasc;
        if (c == 0) {
            kb = &X[(size_t)q * NT1 + 512];
            vb = &X[(size_t)q * NT1 + 1024];
            rp_ = &self_rpe[(size_t)q * PE];
            biasc = 0.f;
        } else if (c < 17) {
            const int idx = topk[qk + c - 1];              // s_load (uniform)
            kb = &X[(bL + idx) * NT1 + 512];
            vb = &X[(bL + idx) * NT1 + 1024];
            rp_ = &rpe[((size_t)qk + (c - 1)) * PE];
            const float d = distances[qk + c - 1];         // s_load (uniform)
            biasc = -(d * d) * inv2sig;
        } else {
            kb = &Kg[(size_t)(bG + c - 17) * INNER];
            vb = &Vg[(size_t)(bG + c - 17) * INNER];
            biasc = gbias;
        }
        ushort8_t kv = *reinterpret_cast<const ushort8_t*>(kb + lane * 8);
        ushort8_t vv = *reinterpret_cast<const ushort8_t*>(vb + lane * 8);
        float4 r4 = {0.f,0.f,0.f,0.f};
        if (c < 17) r4 = *reinterpret_cast<const float4*>(rp_ + r * 4);

        float part = bf2f(kv[0])*qf[0] + bf2f(kv[1])*qf[1]
                   + bf2f(kv[2])*qf[2] + bf2f(kv[3])*qf[3]
                   + bf2f(kv[4])*qf[4] + bf2f(kv[5])*qf[5]
                   + bf2f(kv[6])*qf[6] + bf2f(kv[7])*qf[7];
        if (c < 17)
            part += r4.x*t4[0] + r4.y*t4[1] + r4.z*t4[2] + r4.w*t4[3];
        part = red8_dpp(part);                             // DPP, no DS ops

        const float e = __expf(part * SCALE + biasc);      // no max needed
        denom += e;
        #pragma unroll
        for (int i = 0; i < 8; ++i) acc[i] += e * bf2f(vv[i]);
        if (c < 17) {
            rb[0] += e * r4.x; rb[1] += e * r4.y;
            rb[2] += e * r4.z; rb[3] += e * r4.w;
        }
    }

    const float inv = 1.f / denom;
    ushort4_t ru = { f2bf(rb[0]*inv), f2bf(rb[1]*inv), f2bf(rb[2]*inv), f2bf(rb[3]*inv) };
    *reinterpret_cast<ushort4_t*>(&ob2[(size_t)q * KT2 + 512 + h * 32 + r * 4]) = ru;
    ushort8_t ou = { f2bf(acc[0]*inv), f2bf(acc[1]*inv), f2bf(acc[2]*inv), f2bf(acc[3]*inv),
                     f2bf(acc[4]*inv), f2bf(acc[5]*inv), f2bf(acc[6]*inv), f2bf(acc[7]*inv) };
    *reinterpret_cast<ushort8_t*>(&ob2[(size_t)q * KT2 + lane * 8]) = ou;
}

// ---------------------------------------------------------------------------
extern "C" void kernel_launch(void* const* d_in, const int* in_sizes, int n_in,
                              void* d_out, int out_size, void* d_ws, size_t ws_size,
                              hipStream_t stream)
{
    const float* spatial     = (const float*)d_in[0];
    const int*   topk        = (const int*)  d_in[1];
    const float* rpe         = (const float*)d_in[2];
    const float* self_rpe    = (const float*)d_in[3];
    const float* distances   = (const float*)d_in[4];
    const float* gl          = (const float*)d_in[5];
    const float* Wq          = (const float*)d_in[6];
    const float* Wk          = (const float*)d_in[7];
    const float* Wv          = (const float*)d_in[8];
    const float* Wo          = (const float*)d_in[9];
    const float* bo          = (const float*)d_in[10];
    const float* log_sigma   = (const float*)d_in[11];
    const float* global_bias = (const float*)d_in[12];
    float* out = (float*)d_out;

    char* p = (char*)d_ws;
    float* A   = (float*)p;  p += (size_t)256 * 256 * 4;
    float* M2  = (float*)p;  p += (size_t)256 * 256 * 4;
    u16* Sb    = (u16*)p;    p += (size_t)MM * DD * 2;
    u16* Wt    = (u16*)p;    p += (size_t)NT1 * KT1 * 2;
    u16* Wot   = (u16*)p;    p += (size_t)NT2 * KT2 * 2;
    u16* X     = (u16*)p;    p += (size_t)MM * NT1 * 2;
    u16* ob2   = (u16*)p;    p += (size_t)MM * KT2 * 2;
    u16* Kg    = (u16*)p;    p += (size_t)BB * GG * INNER * 2;
    u16* Vg    = (u16*)p;    p += (size_t)BB * GG * INNER * 2;

    megaprep1<<<1568, 256, 0, stream>>>(Wq, Wk, Wv, Wo, spatial, gl,
                                        A, M2, Sb, Kg, Vg);
    megaprep2<<<160, 256, 0, stream>>>(Wq, Wk, Wv, A, Wo, M2, Wt, Wot);

    mfma_gemm<KT1, 256, NT1, 128, false><<<dim3(MM / 128, NT1 / 128), 256, 0, stream>>>(
        Sb, Wt, X, nullptr, nullptr);

    attn_kernel<<<MM / 4, 256, 0, stream>>>(
        X, Kg, Vg, topk, rpe, self_rpe, distances, log_sigma, global_bias, ob2);

    // BN=32 -> 512 blocks (2/CU) instead of 256 (1/CU): overlap staging drains
    mfma_gemm<KT2, KT2, NT2, 32, true><<<dim3(MM / 128, NT2 / 32), 256, 0, stream>>>(
        ob2, Wot, nullptr, out, bo);
}

// Round 14
// 96.687 us; speedup vs baseline: 2.6604x; 1.0068x over previous
//
#include <hip/hip_runtime.h>
#include <hip/hip_bf16.h>

// Problem constants
#define BB 2
#define LL 4096
#define DD 256
#define KK 16
#define GG 4
#define HH 8
#define DH 64
#define PE 32
#define INNER 512          // H*DH
#define CC 21              // 1 + K + G
#define MM (BB*LL)         // 8192
#define SCALE 0.125f
#define NT1 1792           // QKVT GEMM N  (Q|K|V|T)
#define KT1 256
#define NT2 256            // out GEMM N
#define KT2 768

typedef unsigned short u16;
typedef __attribute__((ext_vector_type(8))) short bf16x8;
typedef __attribute__((ext_vector_type(4))) float f32x4;
typedef unsigned short ushort4_t __attribute__((ext_vector_type(4)));
typedef unsigned short ushort8_t __attribute__((ext_vector_type(8)));

static __device__ __forceinline__ float bf2f(unsigned short u) {
    return __uint_as_float(((unsigned)u) << 16);
}
static __device__ __forceinline__ unsigned short f2bf(float f) {
    unsigned u = __float_as_uint(f);
    unsigned r = u + 0x7fffu + ((u >> 16) & 1u);   // RNE
    return (unsigned short)(r >> 16);
}
static __device__ __forceinline__ void gld_lds16(const void* g, void* l) {
    __builtin_amdgcn_global_load_lds(
        (const __attribute__((address_space(1))) unsigned int*)g,
        (__attribute__((address_space(3))) unsigned int*)l, 16, 0, 0);
}

// 8-lane group sum via DPP (pure VALU, no DS ops).
static __device__ __forceinline__ float red8_dpp(float x) {
    int xi = __float_as_int(x);
    x += __int_as_float(__builtin_amdgcn_update_dpp(0, xi, 0xB1, 0xF, 0xF, true));
    xi = __float_as_int(x);
    x += __int_as_float(__builtin_amdgcn_update_dpp(0, xi, 0x4E, 0xF, 0xF, true));
    xi = __float_as_int(x);
    x += __int_as_float(__builtin_amdgcn_update_dpp(0, xi, 0x141, 0xF, 0xF, true));
    return x;
}

// ---------------------------------------------------------------------------
// megaprep: ALL preprocessing in one kernel (no inter-block dependencies;
// prep_A / prep_M2 scatter their results directly into Wt / Wot transposed,
// eliminating the fp32 A/M2 intermediates and the second prep kernel).
//   [0,256)     prep_A    -> Wt[1536+hp][e]   (bf16 scatter, L2-resident)
//   [256,512)   prep_M2   -> Wot[n][512+hp]   (bf16 scatter)
//   [512,1536)  cast_spatial
//   [1536,1568) gemm_globals
//   [1568,1664) Wq|Wk|Wv feature transpose -> Wt[0..1536)
//   [1664,1696) Wo transpose -> Wot[.][0..512)
// ---------------------------------------------------------------------------
__global__ __launch_bounds__(256) void megaprep(
    const float* __restrict__ Wq, const float* __restrict__ Wk,
    const float* __restrict__ Wv, const float* __restrict__ Wo,
    const float* __restrict__ spatial, const float* __restrict__ gl,
    u16* __restrict__ Sb, u16* __restrict__ Kg, u16* __restrict__ Vg,
    u16* __restrict__ Wt, u16* __restrict__ Wot)
{
    __shared__ float shbuf[64 * 65];     // transpose tile; low 512 reused below
    const int bid = blockIdx.x;
    const int tid = threadIdx.x;

    if (bid < 256) {                       // ---- prep_A (direct transposed)
        const int e = bid;
        shbuf[tid]       = Wq[e * INNER + tid];
        shbuf[tid + 256] = Wq[e * INNER + 256 + tid];
        __syncthreads();
        const int h = tid >> 5, p = tid & 31;
        const float* __restrict__ wr = &Wk[(size_t)(DD + p) * INNER + h * DH];
        const float* __restrict__ qh = &shbuf[h * DH];
        float s = 0.f;
        #pragma unroll 8
        for (int d = 0; d < DH; ++d) s += wr[d] * qh[d];
        Wt[(size_t)(1536 + tid) * KT1 + e] = f2bf(s);
    } else if (bid < 512) {                // ---- prep_M2 (direct transposed)
        const int hp = bid - 256;
        const int h = hp >> 5, p = hp & 31;
        if (tid < DH) shbuf[tid] = Wv[(size_t)(DD + p) * INNER + h * DH + tid];
        __syncthreads();
        float s = 0.f;
        #pragma unroll 8
        for (int d = 0; d < DH; ++d) s += shbuf[d] * Wo[(size_t)(h * DH + d) * DD + tid];
        Wot[(size_t)tid * KT2 + 512 + hp] = f2bf(s);
    } else if (bid < 1536) {               // ---- cast_spatial
        const size_t i = ((size_t)(bid - 512) * 256 + tid) * 8;
        float4 a = *reinterpret_cast<const float4*>(&spatial[i]);
        float4 b = *reinterpret_cast<const float4*>(&spatial[i + 4]);
        ushort8_t v = { f2bf(a.x), f2bf(a.y), f2bf(a.z), f2bf(a.w),
                        f2bf(b.x), f2bf(b.y), f2bf(b.z), f2bf(b.w) };
        *reinterpret_cast<ushort8_t*>(&Sb[i]) = v;
    } else if (bid < 1568) {               // ---- gemm_globals
        const int local = bid - 1536;
        const int bg = local >> 2;
        const int col = (local & 3) * 128 + (tid & 127);
        const bool isv = tid >= 128;
        const float* __restrict__ W = isv ? Wv : Wk;
        const float* __restrict__ x = &gl[bg * DD];
        float s = 0.f;
        #pragma unroll 4
        for (int k = 0; k < DD; ++k) s += x[k] * W[(size_t)k * INNER + col];
        if (isv) Vg[bg * INNER + col] = f2bf(s);
        else     Kg[bg * INNER + col] = f2bf(s);
    } else {                               // ---- 64x64 LDS transposes
        float (*tile)[65] = reinterpret_cast<float (*)[65]>(shbuf);
        const float* src; int ld, nloc, n0, k0, ldo; u16* dstbase; int kt;
        if (bid < 1664) {                  // Wq|Wk|Wv -> Wt
            const int local = bid - 1568;  // 96 blocks: 24 n-tiles x 4 k-tiles
            n0 = (local % 24) * 64; k0 = (local / 24) * 64;
            if (n0 < 512)       { src = Wq; nloc = n0; }
            else if (n0 < 1024) { src = Wk; nloc = n0 - 512; }
            else                { src = Wv; nloc = n0 - 1024; }
            ld = INNER; dstbase = Wt; ldo = KT1; kt = k0;
        } else {                           // Wo -> Wot[.][0..512)
            const int local = bid - 1664;  // 32 blocks: 4 n-tiles x 8 k-tiles
            n0 = (local % 4) * 64; k0 = (local / 4) * 64;
            src = Wo; ld = DD; nloc = n0; kt = k0;
            dstbase = Wot; ldo = KT2;
        }
        const int tk = tid >> 4;
        const int tn = (tid & 15) * 4;
        #pragma unroll
        for (int rep = 0; rep < 4; ++rep) {
            const int k = kt + tk + rep * 16;
            float4 v = *reinterpret_cast<const float4*>(&src[(size_t)k * ld + nloc + tn]);
            tile[tk + rep * 16][tn + 0] = v.x; tile[tk + rep * 16][tn + 1] = v.y;
            tile[tk + rep * 16][tn + 2] = v.z; tile[tk + rep * 16][tn + 3] = v.w;
        }
        __syncthreads();
        const int wn = tid >> 2;
        const int wk = (tid & 3) * 16;
        ushort8_t o0, o1;
        #pragma unroll
        for (int i = 0; i < 8; ++i) o0[i] = f2bf(tile[wk + i][wn]);
        #pragma unroll
        for (int i = 0; i < 8; ++i) o1[i] = f2bf(tile[wk + 8 + i][wn]);
        u16* dst = &dstbase[(size_t)(n0 + wn) * ldo + k0 + wk];
        *reinterpret_cast<ushort8_t*>(dst)     = o0;
        *reinterpret_cast<ushort8_t*>(dst + 8) = o1;
    }
}

// ---------------------------------------------------------------------------
// mfma_gemm: proven m97-style loop; NEW coalesced epilogue via LDS bounce
// (reuses the As/Bs pool; 16B-block XOR swizzle avoids bank conflicts).
// ---------------------------------------------------------------------------
template<int KT, int LDA, int NTOT, int BN, bool F32OUT>
__global__ __launch_bounds__(256) void mfma_gemm(
    const u16* __restrict__ A, const u16* __restrict__ Bt,
    u16* __restrict__ outB, float* __restrict__ outF,
    const float* __restrict__ bias)
{
    constexpr int WNT = BN / 2;
    constexpr int BJ  = WNT / 16;
    constexpr int BCH = BN / 8;

    __shared__ uint32_t smem32[(128 * 64 + BN * 64) / 2];
    u16* As = reinterpret_cast<u16*>(smem32);
    u16* Bs = As + 128 * 64;

    const int tid  = threadIdx.x;
    const int lane = tid & 63;
    const int w    = tid >> 6;
    const int wr   = w >> 1, wc = w & 1;
    const int m0 = blockIdx.x * 128;
    const int n0 = blockIdx.y * BN;
    const int fr = lane & 15, fq = lane >> 4;

    f32x4 acc[4][BJ];
    #pragma unroll
    for (int i = 0; i < 4; ++i)
        #pragma unroll
        for (int j = 0; j < BJ; ++j)
            acc[i][j] = (f32x4){0.f, 0.f, 0.f, 0.f};

    for (int t = 0; t < KT / 64; ++t) {
        const int k0 = t * 64;
        #pragma unroll
        for (int cc = 0; cc < 4; ++cc) {
            const int chunk = w + cc * 4;
            gld_lds16(A + (size_t)(m0 + chunk * 8 + (lane >> 3)) * LDA + k0 + (lane & 7) * 8,
                      (char*)As + chunk * 1024);
        }
        #pragma unroll
        for (int cc = 0; cc < BCH / 4; ++cc) {
            const int chunk = w + cc * 4;
            gld_lds16(Bt + (size_t)(n0 + chunk * 8 + (lane >> 3)) * KT + k0 + (lane & 7) * 8,
                      (char*)Bs + chunk * 1024);
        }
        __syncthreads();
        #pragma unroll
        for (int ks = 0; ks < 2; ++ks) {
            bf16x8 av[4], bv[BJ];
            #pragma unroll
            for (int i = 0; i < 4; ++i)
                av[i] = *reinterpret_cast<const bf16x8*>(
                    &As[(wr * 64 + i * 16 + fr) * 64 + ks * 32 + fq * 8]);
            #pragma unroll
            for (int j = 0; j < BJ; ++j)
                bv[j] = *reinterpret_cast<const bf16x8*>(
                    &Bs[(wc * WNT + j * 16 + fr) * 64 + ks * 32 + fq * 8]);
            #pragma unroll
            for (int i = 0; i < 4; ++i)
                #pragma unroll
                for (int j = 0; j < BJ; ++j)
                    acc[i][j] = __builtin_amdgcn_mfma_f32_16x16x32_bf16(
                        av[i], bv[j], acc[i][j], 0, 0, 0);
        }
        __syncthreads();
    }

    // ---------------- coalesced epilogue (LDS bounce) ----------------
    if constexpr (!F32OUT) {
        // bf16 tile 128 x BN in u16 (fits: (128+BN)*64 u16 >= 128*BN for BN<=128)
        u16* ep = As;
        #pragma unroll
        for (int i = 0; i < 4; ++i)
            #pragma unroll
            for (int j = 0; j < BJ; ++j)
                #pragma unroll
                for (int rgi = 0; rgi < 4; ++rgi) {
                    const int rl = wr * 64 + i * 16 + fq * 4 + rgi;
                    const int cl = wc * WNT + j * 16 + fr;
                    const int cb = (cl >> 3) ^ ((rl >> 2) & (BN / 8 - 1));
                    ep[rl * BN + (cb << 3) + (cl & 7)] = f2bf(acc[i][j][rgi]);
                }
        __syncthreads();
        constexpr int PASS = (128 * BN) / (256 * 8);
        #pragma unroll
        for (int p = 0; p < PASS; ++p) {
            const int flat = (p * 256 + tid) * 8;
            const int rl = flat / BN, cl = flat % BN;
            const int cb = (cl >> 3) ^ ((rl >> 2) & (BN / 8 - 1));
            *reinterpret_cast<ushort8_t*>(&outB[(size_t)(m0 + rl) * NTOT + n0 + cl]) =
                *reinterpret_cast<const ushort8_t*>(&ep[rl * BN + (cb << 3)]);
        }
    } else {
        // fp32 tile 128 x BN (BN=32: 16 KB <= pool 20 KB)
        float* epf = reinterpret_cast<float*>(smem32);
        #pragma unroll
        for (int i = 0; i < 4; ++i)
            #pragma unroll
            for (int j = 0; j < BJ; ++j)
                #pragma unroll
                for (int rgi = 0; rgi < 4; ++rgi) {
                    const int rl = wr * 64 + i * 16 + fq * 4 + rgi;
                    const int cl = wc * WNT + j * 16 + fr;
                    const int cb = (cl >> 2) ^ ((rl >> 2) & (BN / 4 - 1));
                    epf[rl * BN + (cb << 2) + (cl & 3)] = acc[i][j][rgi];
                }
        __syncthreads();
        constexpr int PASS = (128 * BN) / (256 * 4);
        #pragma unroll
        for (int p = 0; p < PASS; ++p) {
            const int flat = (p * 256 + tid) * 4;
            const int rl = flat / BN, cl = flat % BN;
            const int cb = (cl >> 2) ^ ((rl >> 2) & (BN / 4 - 1));
            float4 v = *reinterpret_cast<const float4*>(&epf[rl * BN + (cb << 2)]);
            const float4 bb = *reinterpret_cast<const float4*>(&bias[n0 + cl]);
            v.x += bb.x; v.y += bb.y; v.z += bb.z; v.w += bb.w;
            *reinterpret_cast<float4*>(&outF[(size_t)(m0 + rl) * NTOT + n0 + cl]) = v;
        }
    }
}

// ---------------------------------------------------------------------------
// attn: UNCHANGED from R13 (one wave/query, single-pass no-max softmax,
// DPP reduce, natural register allocation — forced min-waves bounds spill).
// ---------------------------------------------------------------------------
__global__ __launch_bounds__(256) void attn_kernel(
    const u16* __restrict__ X, const u16* __restrict__ Kg,
    const u16* __restrict__ Vg, const int* __restrict__ topk,
    const float* __restrict__ rpe, const float* __restrict__ self_rpe,
    const float* __restrict__ distances, const float* __restrict__ log_sigma,
    const float* __restrict__ global_bias, u16* __restrict__ ob2)
{
    const int lane = threadIdx.x & 63;
    const int bid  = blockIdx.x;
    const int xcd  = bid & 7;
    const int slot = bid >> 3;                       // 0..255
    const int qblk = (xcd >> 2) * 1024 + slot * 4 + (xcd & 3);
    const int q = __builtin_amdgcn_readfirstlane(qblk * 4 + (threadIdx.x >> 6));
    const int b = q >> 12;
    const int h = lane >> 3;
    const int r = lane & 7;
    const int qk = q * KK;
    const size_t bL = (size_t)b * LL;
    const int bG = b * GG;

    float qf[8];
    {
        ushort8_t qv = *reinterpret_cast<const ushort8_t*>(&X[(size_t)q * NT1 + lane * 8]);
        #pragma unroll
        for (int j = 0; j < 8; ++j) qf[j] = bf2f(qv[j]);
    }
    float t4[4];
    {
        ushort4_t tu = *reinterpret_cast<const ushort4_t*>(
            &X[(size_t)q * NT1 + 1536 + h * 32 + r * 4]);
        t4[0] = bf2f(tu[0]); t4[1] = bf2f(tu[1]);
        t4[2] = bf2f(tu[2]); t4[3] = bf2f(tu[3]);
    }

    const float inv2sig = 0.5f * __expf(-2.f * log_sigma[h]);
    const float gbias   = global_bias[0];

    float denom = 0.f;
    float acc[8] = {0.f,0.f,0.f,0.f,0.f,0.f,0.f,0.f};
    float rb[4]  = {0.f,0.f,0.f,0.f};

    #pragma unroll
    for (int c = 0; c < CC; ++c) {
        const u16 *kb, *vb;
        const float* rp_ = nullptr;
        float biasc;
        if (c == 0) {
            kb = &X[(size_t)q * NT1 + 512];
            vb = &X[(size_t)q * NT1 + 1024];
            rp_ = &self_rpe[(size_t)q * PE];
            biasc = 0.f;
        } else if (c < 17) {
            const int idx = topk[qk + c - 1];              // s_load (uniform)
            kb = &X[(bL + idx) * NT1 + 512];
            vb = &X[(bL + idx) * NT1 + 1024];
            rp_ = &rpe[((size_t)qk + (c - 1)) * PE];
            const float d = distances[qk + c - 1];         // s_load (uniform)
            biasc = -(d * d) * inv2sig;
        } else {
            kb = &Kg[(size_t)(bG + c - 17) * INNER];
            vb = &Vg[(size_t)(bG + c - 17) * INNER];
            biasc = gbias;
        }
        ushort8_t kv = *reinterpret_cast<const ushort8_t*>(kb + lane * 8);
        ushort8_t vv = *reinterpret_cast<const ushort8_t*>(vb + lane * 8);
        float4 r4 = {0.f,0.f,0.f,0.f};
        if (c < 17) r4 = *reinterpret_cast<const float4*>(rp_ + r * 4);

        float part = bf2f(kv[0])*qf[0] + bf2f(kv[1])*qf[1]
                   + bf2f(kv[2])*qf[2] + bf2f(kv[3])*qf[3]
                   + bf2f(kv[4])*qf[4] + bf2f(kv[5])*qf[5]
                   + bf2f(kv[6])*qf[6] + bf2f(kv[7])*qf[7];
        if (c < 17)
            part += r4.x*t4[0] + r4.y*t4[1] + r4.z*t4[2] + r4.w*t4[3];
        part = red8_dpp(part);                             // DPP, no DS ops

        const float e = __expf(part * SCALE + biasc);      // no max needed
        denom += e;
        #pragma unroll
        for (int i = 0; i < 8; ++i) acc[i] += e * bf2f(vv[i]);
        if (c < 17) {
            rb[0] += e * r4.x; rb[1] += e * r4.y;
            rb[2] += e * r4.z; rb[3] += e * r4.w;
        }
    }

    const float inv = 1.f / denom;
    ushort4_t ru = { f2bf(rb[0]*inv), f2bf(rb[1]*inv), f2bf(rb[2]*inv), f2bf(rb[3]*inv) };
    *reinterpret_cast<ushort4_t*>(&ob2[(size_t)q * KT2 + 512 + h * 32 + r * 4]) = ru;
    ushort8_t ou = { f2bf(acc[0]*inv), f2bf(acc[1]*inv), f2bf(acc[2]*inv), f2bf(acc[3]*inv),
                     f2bf(acc[4]*inv), f2bf(acc[5]*inv), f2bf(acc[6]*inv), f2bf(acc[7]*inv) };
    *reinterpret_cast<ushort8_t*>(&ob2[(size_t)q * KT2 + lane * 8]) = ou;
}

// ---------------------------------------------------------------------------
extern "C" void kernel_launch(void* const* d_in, const int* in_sizes, int n_in,
                              void* d_out, int out_size, void* d_ws, size_t ws_size,
                              hipStream_t stream)
{
    const float* spatial     = (const float*)d_in[0];
    const int*   topk        = (const int*)  d_in[1];
    const float* rpe         = (const float*)d_in[2];
    const float* self_rpe    = (const float*)d_in[3];
    const float* distances   = (const float*)d_in[4];
    const float* gl          = (const float*)d_in[5];
    const float* Wq          = (const float*)d_in[6];
    const float* Wk          = (const float*)d_in[7];
    const float* Wv          = (const float*)d_in[8];
    const float* Wo          = (const float*)d_in[9];
    const float* bo          = (const float*)d_in[10];
    const float* log_sigma   = (const float*)d_in[11];
    const float* global_bias = (const float*)d_in[12];
    float* out = (float*)d_out;

    char* p = (char*)d_ws;
    u16* Sb    = (u16*)p;    p += (size_t)MM * DD * 2;
    u16* Wt    = (u16*)p;    p += (size_t)NT1 * KT1 * 2;
    u16* Wot   = (u16*)p;    p += (size_t)NT2 * KT2 * 2;
    u16* X     = (u16*)p;    p += (size_t)MM * NT1 * 2;
    u16* ob2   = (u16*)p;    p += (size_t)MM * KT2 * 2;
    u16* Kg    = (u16*)p;    p += (size_t)BB * GG * INNER * 2;
    u16* Vg    = (u16*)p;    p += (size_t)BB * GG * INNER * 2;

    megaprep<<<1696, 256, 0, stream>>>(Wq, Wk, Wv, Wo, spatial, gl,
                                       Sb, Kg, Vg, Wt, Wot);

    mfma_gemm<KT1, 256, NT1, 128, false><<<dim3(MM / 128, NT1 / 128), 256, 0, stream>>>(
        Sb, Wt, X, nullptr, nullptr);

    attn_kernel<<<MM / 4, 256, 0, stream>>>(
        X, Kg, Vg, topk, rpe, self_rpe, distances, log_sigma, global_bias, ob2);

    mfma_gemm<KT2, KT2, NT2, 32, true><<<dim3(MM / 128, NT2 / 32), 256, 0, stream>>>(
        ob2, Wot, nullptr, out, bo);
}